// Round 1
// baseline (301.884 us; speedup 1.0000x reference)
//
#include <hip/hip_runtime.h>
#include <hip/hip_bf16.h>
#include <cstdint>
#include <cstddef>

typedef __attribute__((ext_vector_type(8))) short short8;
typedef __attribute__((ext_vector_type(4))) float f32x4;

__device__ __forceinline__ short bfbits(float f) {
    __bf16 h = (__bf16)f;
    return __builtin_bit_cast(short, h);
}
__device__ __forceinline__ float bf2f(unsigned short b) {
    union { uint32_t u; float f; } v; v.u = ((uint32_t)b) << 16;
    return v.f;
}

// ---------- kernel 0: weight transpose + bf16 convert ----------
// wt[mat][n][k] = bf16(W[mat][k][n]),  mat: 0=Wq 1=Wk 2=Wv 3=Wg 4=Wo
__global__ void wt_kernel(const float* __restrict__ Wq, const float* __restrict__ Wk,
                          const float* __restrict__ Wv, const float* __restrict__ Wg,
                          const float* __restrict__ Wo, unsigned short* __restrict__ wt)
{
    int mat = blockIdx.x >> 8;
    int n   = blockIdx.x & 255;
    const float* W = (mat==0)?Wq:(mat==1)?Wk:(mat==2)?Wv:(mat==3)?Wg:Wo;
    int k = threadIdx.x;
    wt[((size_t)mat*256 + n)*256 + k] = (unsigned short)bfbits(W[(size_t)k*256 + n]);
}

// ---------- kernel 1: fused projections ----------
// grid = 512 row-blocks * 4 projections. p: 0=Q 1=K 2=V 3=G(gate)
// Q/K/V written to [r][h][s][32] bf16; G = sigmoid(qx@Wg+bg) to [rq][256] bf16.
__global__ __launch_bounds__(256) void proj_kernel(
    const float* __restrict__ qx, const float* __restrict__ kx, const float* __restrict__ vx,
    const float* __restrict__ bg, const unsigned short* __restrict__ wt,
    unsigned short* __restrict__ Qa, unsigned short* __restrict__ Ka,
    unsigned short* __restrict__ Va, unsigned short* __restrict__ G)
{
    int bx = blockIdx.x;
    int p  = bx & 3;
    int rb = bx >> 2;
    int row0 = rb * 64;
    int tid = threadIdx.x;
    int w = tid >> 6, lane = tid & 63;
    int c = lane & 15, g = lane >> 4;
    int col0 = w * 64;

    const float* X = (p == 1) ? kx : (p == 2) ? vx : qx;
    const unsigned short* Wt = wt + (size_t)p * 65536;

    f32x4 acc[4][4];
    #pragma unroll
    for (int m = 0; m < 4; m++)
        #pragma unroll
        for (int n = 0; n < 4; n++)
            acc[m][n] = 0.0f;

    for (int step = 0; step < 8; ++step) {
        int koff = step * 32 + g * 8;
        short8 a[4], b[4];
        #pragma unroll
        for (int m = 0; m < 4; m++) {
            const float* src = X + (size_t)(row0 + m*16 + c) * 256 + koff;
            f32x4 lo = *(const f32x4*)src;
            f32x4 hi = *(const f32x4*)(src + 4);
            short8 t;
            t[0]=bfbits(lo[0]); t[1]=bfbits(lo[1]); t[2]=bfbits(lo[2]); t[3]=bfbits(lo[3]);
            t[4]=bfbits(hi[0]); t[5]=bfbits(hi[1]); t[6]=bfbits(hi[2]); t[7]=bfbits(hi[3]);
            a[m] = t;
        }
        #pragma unroll
        for (int n = 0; n < 4; n++)
            b[n] = *(const short8*)(Wt + (size_t)(col0 + n*16 + c) * 256 + koff);
        #pragma unroll
        for (int m = 0; m < 4; m++)
            #pragma unroll
            for (int n = 0; n < 4; n++)
                acc[m][n] = __builtin_amdgcn_mfma_f32_16x16x32_bf16(a[m], b[n], acc[m][n], 0, 0, 0);
    }

    // epilogue
    #pragma unroll
    for (int m = 0; m < 4; m++) {
        #pragma unroll
        for (int n = 0; n < 4; n++) {
            int col = col0 + n*16 + c;
            #pragma unroll
            for (int i = 0; i < 4; i++) {
                int rr = row0 + m*16 + g*4 + i;
                float v = acc[m][n][i];
                if (p == 3) {
                    float s = 1.0f / (1.0f + __expf(-(v + bg[col])));
                    G[(size_t)rr * 256 + col] = (unsigned short)bfbits(s);
                } else {
                    int r_ = rr >> 8, s_ = rr & 255;
                    int h_ = col >> 5, d_ = col & 31;
                    unsigned short* dst = (p == 0) ? Qa : (p == 1) ? Ka : Va;
                    dst[((size_t)((r_*8 + h_)*256 + s_)) * 32 + d_] = (unsigned short)bfbits(v);
                }
            }
        }
    }
}

// ---------- kernel 2: attention per (r,h) ----------
// S = QK^T*norm + bias ; P = softmax(S) ; O = P V ; og = O * gate
__global__ __launch_bounds__(256) void attn_kernel(
    const unsigned short* __restrict__ Qa, const unsigned short* __restrict__ Ka,
    const unsigned short* __restrict__ Va, const unsigned short* __restrict__ G,
    const float* __restrict__ bias, unsigned short* __restrict__ og)
{
    __shared__ unsigned short Ks[256 * 40];   // [k][d] padded to 40 elems
    __shared__ unsigned short Vt[32 * 264];   // [d][k] padded to 264 elems
    __shared__ unsigned short Ps[4][16 * 136];// per-wave [q][k-half] padded

    int bx = blockIdx.x;
    int r = bx >> 3, h = bx & 7;
    int tid = threadIdx.x;
    int w = tid >> 6, lane = tid & 63;
    int c = lane & 15, g = lane >> 4;

    size_t base = ((size_t)(r*8 + h)) * 256 * 32;
    const unsigned short* Kg = Ka + base;
    const unsigned short* Vg = Va + base;

    // stage K (row-major, padded) and V (transposed)
    #pragma unroll
    for (int pass = 0; pass < 4; ++pass) {
        int idx = tid * 8 + pass * 2048;
        int k = idx >> 5, d = idx & 31;
        short8 vk = *(const short8*)(Kg + idx);
        *(short8*)(&Ks[k * 40 + d]) = vk;
        short8 vv = *(const short8*)(Vg + idx);
        #pragma unroll
        for (int j = 0; j < 8; j++) Vt[(d + j) * 264 + k] = (unsigned short)vv[j];
    }
    __syncthreads();

    const float nrm = 0.17677669529663687f;
    const float* biash = bias + (size_t)h * 65536;
    unsigned short* Pw = &Ps[w][0];

    for (int m = 0; m < 4; m++) {
        int qrow = w * 64 + m * 16;
        short8 qa = *(const short8*)(Qa + base + (size_t)(qrow + c) * 32 + g * 8);

        f32x4 s[16];
        #pragma unroll
        for (int n = 0; n < 16; n++) {
            short8 kb = *(const short8*)(&Ks[(n*16 + c) * 40 + g * 8]);
            f32x4 z = 0.0f;
            s[n] = __builtin_amdgcn_mfma_f32_16x16x32_bf16(qa, kb, z, 0, 0, 0);
        }

        // bias + scale, rowmax
        float mx[4] = {-1e30f, -1e30f, -1e30f, -1e30f};
        #pragma unroll
        for (int n = 0; n < 16; n++) {
            #pragma unroll
            for (int i = 0; i < 4; i++) {
                int rq = qrow + g*4 + i;
                float val = s[n][i] * nrm + biash[(size_t)rq * 256 + n*16 + c];
                s[n][i] = val;
                mx[i] = fmaxf(mx[i], val);
            }
        }
        #pragma unroll
        for (int i = 0; i < 4; i++) {
            mx[i] = fmaxf(mx[i], __shfl_xor(mx[i], 1));
            mx[i] = fmaxf(mx[i], __shfl_xor(mx[i], 2));
            mx[i] = fmaxf(mx[i], __shfl_xor(mx[i], 4));
            mx[i] = fmaxf(mx[i], __shfl_xor(mx[i], 8));
        }
        float sum[4] = {0.f, 0.f, 0.f, 0.f};
        #pragma unroll
        for (int n = 0; n < 16; n++) {
            #pragma unroll
            for (int i = 0; i < 4; i++) {
                float pv = __expf(s[n][i] - mx[i]);
                s[n][i] = pv;
                sum[i] += pv;
            }
        }
        #pragma unroll
        for (int i = 0; i < 4; i++) {
            sum[i] += __shfl_xor(sum[i], 1);
            sum[i] += __shfl_xor(sum[i], 2);
            sum[i] += __shfl_xor(sum[i], 4);
            sum[i] += __shfl_xor(sum[i], 8);
        }
        float inv[4];
        #pragma unroll
        for (int i = 0; i < 4; i++) inv[i] = 1.0f / sum[i];

        // PV in two k-halves through per-wave LDS
        f32x4 o[2];
        o[0] = 0.0f; o[1] = 0.0f;
        #pragma unroll
        for (int half = 0; half < 2; ++half) {
            #pragma unroll
            for (int nn = 0; nn < 8; nn++) {
                int n = half * 8 + nn;
                #pragma unroll
                for (int i = 0; i < 4; i++)
                    Pw[(g*4 + i) * 136 + nn*16 + c] = (unsigned short)bfbits(s[n][i]);
            }
            #pragma unroll
            for (int step = 0; step < 4; ++step) {
                short8 pa = *(const short8*)(&Pw[c * 136 + step*32 + g*8]);
                int kbase = half * 128 + step * 32;
                #pragma unroll
                for (int n2 = 0; n2 < 2; n2++) {
                    short8 vb = *(const short8*)(&Vt[(n2*16 + c) * 264 + kbase + g*8]);
                    o[n2] = __builtin_amdgcn_mfma_f32_16x16x32_bf16(pa, vb, o[n2], 0, 0, 0);
                }
            }
        }

        // gate + write og [rq][h*32+d]
        #pragma unroll
        for (int n2 = 0; n2 < 2; n2++) {
            #pragma unroll
            for (int i = 0; i < 4; i++) {
                int rq = qrow + g*4 + i;
                size_t gidx = ((size_t)(r*256 + rq)) * 256 + h*32 + n2*16 + c;
                float gate = bf2f(G[gidx]);
                float val = o[n2][i] * inv[i] * gate;
                og[gidx] = (unsigned short)bfbits(val);
            }
        }
    }
}

// ---------- kernel 3: output projection ----------
__global__ __launch_bounds__(256) void oproj_kernel(
    const unsigned short* __restrict__ og, const unsigned short* __restrict__ wt_o,
    const float* __restrict__ bo, float* __restrict__ out)
{
    int rb = blockIdx.x;
    int row0 = rb * 64;
    int tid = threadIdx.x;
    int w = tid >> 6, lane = tid & 63;
    int c = lane & 15, g = lane >> 4;
    int col0 = w * 64;

    f32x4 acc[4][4];
    #pragma unroll
    for (int m = 0; m < 4; m++)
        #pragma unroll
        for (int n = 0; n < 4; n++)
            acc[m][n] = 0.0f;

    for (int step = 0; step < 8; ++step) {
        int koff = step * 32 + g * 8;
        short8 a[4], b[4];
        #pragma unroll
        for (int m = 0; m < 4; m++)
            a[m] = *(const short8*)(og + (size_t)(row0 + m*16 + c) * 256 + koff);
        #pragma unroll
        for (int n = 0; n < 4; n++)
            b[n] = *(const short8*)(wt_o + (size_t)(col0 + n*16 + c) * 256 + koff);
        #pragma unroll
        for (int m = 0; m < 4; m++)
            #pragma unroll
            for (int n = 0; n < 4; n++)
                acc[m][n] = __builtin_amdgcn_mfma_f32_16x16x32_bf16(a[m], b[n], acc[m][n], 0, 0, 0);
    }

    #pragma unroll
    for (int m = 0; m < 4; m++) {
        #pragma unroll
        for (int n = 0; n < 4; n++) {
            int col = col0 + n*16 + c;
            float bv = bo[col];
            #pragma unroll
            for (int i = 0; i < 4; i++) {
                int row = row0 + m*16 + g*4 + i;
                out[(size_t)row * 256 + col] = acc[m][n][i] + bv;
            }
        }
    }
}

extern "C" void kernel_launch(void* const* d_in, const int* in_sizes, int n_in,
                              void* d_out, int out_size, void* d_ws, size_t ws_size,
                              hipStream_t stream) {
    const float* qx   = (const float*)d_in[0];
    const float* kx   = (const float*)d_in[1];
    const float* vx   = (const float*)d_in[2];
    const float* bias = (const float*)d_in[3];
    const float* Wq   = (const float*)d_in[4];
    const float* Wk   = (const float*)d_in[5];
    const float* Wv   = (const float*)d_in[6];
    const float* Wo   = (const float*)d_in[7];
    const float* bo   = (const float*)d_in[8];
    const float* Wg   = (const float*)d_in[9];
    const float* bg   = (const float*)d_in[10];

    uint8_t* ws = (uint8_t*)d_ws;
    unsigned short* wt = (unsigned short*)ws;                         // 5*65536 elems
    unsigned short* Qa = (unsigned short*)(ws + (1u<<20));            // 16 MB each
    unsigned short* Ka = (unsigned short*)(ws + (1u<<20) + 1u*(1u<<24));
    unsigned short* Va = (unsigned short*)(ws + (1u<<20) + 2u*(1u<<24));
    unsigned short* G  = (unsigned short*)(ws + (1u<<20) + 3u*(1u<<24));
    unsigned short* og = (unsigned short*)(ws + (1u<<20) + 4u*(1u<<24));

    hipLaunchKernelGGL(wt_kernel, dim3(1280), dim3(256), 0, stream, Wq, Wk, Wv, Wg, Wo, wt);
    hipLaunchKernelGGL(proj_kernel, dim3(2048), dim3(256), 0, stream, qx, kx, vx, bg, wt, Qa, Ka, Va, G);
    hipLaunchKernelGGL(attn_kernel, dim3(1024), dim3(256), 0, stream, Qa, Ka, Va, G, bias, og);
    hipLaunchKernelGGL(oproj_kernel, dim3(512), dim3(256), 0, stream, og, wt + 4*65536, bo, (float*)d_out);
}

// Round 3
// 256.744 us; speedup vs baseline: 1.1758x; 1.1758x over previous
//
#include <hip/hip_runtime.h>
#include <hip/hip_bf16.h>
#include <cstdint>
#include <cstddef>

typedef __attribute__((ext_vector_type(8))) short short8;
typedef __attribute__((ext_vector_type(4))) short s16x4;
typedef __attribute__((ext_vector_type(4))) float f32x4;
typedef __attribute__((ext_vector_type(4))) unsigned int u32x4;

__device__ __forceinline__ short bfbits(float f) {
    __bf16 h = (__bf16)f;
    return __builtin_bit_cast(short, h);
}
__device__ __forceinline__ float bf2f(unsigned short b) {
    union { uint32_t u; float f; } v; v.u = ((uint32_t)b) << 16;
    return v.f;
}
__device__ __forceinline__ unsigned int pack2(float x, float y) {
    return (unsigned int)(unsigned short)bfbits(x) |
           ((unsigned int)(unsigned short)bfbits(y) << 16);
}

// ---------- kernel 0: weight transpose + bf16 convert ----------
// wt[mat][n][k] = bf16(W[mat][k][n]),  mat: 0=Wq 1=Wk 2=Wv 3=Wg 4=Wo
__global__ void wt_kernel(const float* __restrict__ Wq, const float* __restrict__ Wk,
                          const float* __restrict__ Wv, const float* __restrict__ Wg,
                          const float* __restrict__ Wo, unsigned short* __restrict__ wt)
{
    int mat = blockIdx.x >> 8;
    int n   = blockIdx.x & 255;
    const float* W = (mat==0)?Wq:(mat==1)?Wk:(mat==2)?Wv:(mat==3)?Wg:Wo;
    int k = threadIdx.x;
    wt[((size_t)mat*256 + n)*256 + k] = (unsigned short)bfbits(W[(size_t)k*256 + n]);
}

// ---------- kernel 1: fused projections ----------
// grid = 512 row-blocks * 4 projections. p: 0=Q 1=K 2=V 3=G(gate)
// Q/K written to [r][h][s][32] bf16; V written TRANSPOSED to [r][h][d][s] bf16;
// G = sigmoid(qx@Wg+bg) to [rq][256] bf16.
__global__ __launch_bounds__(256) void proj_kernel(
    const float* __restrict__ qx, const float* __restrict__ kx, const float* __restrict__ vx,
    const float* __restrict__ bg, const unsigned short* __restrict__ wt,
    unsigned short* __restrict__ Qa, unsigned short* __restrict__ Ka,
    unsigned short* __restrict__ Va, unsigned short* __restrict__ G)
{
    int bx = blockIdx.x;
    int p  = bx & 3;
    int rb = bx >> 2;
    int row0 = rb * 64;
    int tid = threadIdx.x;
    int w = tid >> 6, lane = tid & 63;
    int c = lane & 15, g = lane >> 4;
    int col0 = w * 64;

    const float* X = (p == 1) ? kx : (p == 2) ? vx : qx;
    const unsigned short* Wt = wt + (size_t)p * 65536;

    f32x4 acc[4][4];
    #pragma unroll
    for (int m = 0; m < 4; m++)
        #pragma unroll
        for (int n = 0; n < 4; n++)
            acc[m][n] = 0.0f;

    for (int step = 0; step < 8; ++step) {
        int koff = step * 32 + g * 8;
        short8 a[4], b[4];
        #pragma unroll
        for (int m = 0; m < 4; m++) {
            const float* src = X + (size_t)(row0 + m*16 + c) * 256 + koff;
            f32x4 lo = *(const f32x4*)src;
            f32x4 hi = *(const f32x4*)(src + 4);
            short8 t;
            t[0]=bfbits(lo[0]); t[1]=bfbits(lo[1]); t[2]=bfbits(lo[2]); t[3]=bfbits(lo[3]);
            t[4]=bfbits(hi[0]); t[5]=bfbits(hi[1]); t[6]=bfbits(hi[2]); t[7]=bfbits(hi[3]);
            a[m] = t;
        }
        #pragma unroll
        for (int n = 0; n < 4; n++)
            b[n] = *(const short8*)(Wt + (size_t)(col0 + n*16 + c) * 256 + koff);
        #pragma unroll
        for (int m = 0; m < 4; m++)
            #pragma unroll
            for (int n = 0; n < 4; n++)
                acc[m][n] = __builtin_amdgcn_mfma_f32_16x16x32_bf16(a[m], b[n], acc[m][n], 0, 0, 0);
    }

    // epilogue
    #pragma unroll
    for (int m = 0; m < 4; m++) {
        #pragma unroll
        for (int n = 0; n < 4; n++) {
            int col = col0 + n*16 + c;
            #pragma unroll
            for (int i = 0; i < 4; i++) {
                int rr = row0 + m*16 + g*4 + i;
                float v = acc[m][n][i];
                if (p == 3) {
                    float s = 1.0f / (1.0f + __expf(-(v + bg[col])));
                    G[(size_t)rr * 256 + col] = (unsigned short)bfbits(s);
                } else {
                    int r_ = rr >> 8, s_ = rr & 255;
                    int h_ = col >> 5, d_ = col & 31;
                    if (p == 2) {
                        // transposed: Va[r][h][d][s]
                        Va[((size_t)((r_*8 + h_)*32 + d_)) * 256 + s_] = (unsigned short)bfbits(v);
                    } else {
                        unsigned short* dst = (p == 0) ? Qa : Ka;
                        dst[((size_t)((r_*8 + h_)*256 + s_)) * 32 + d_] = (unsigned short)bfbits(v);
                    }
                }
            }
        }
    }
}

// ---------- kernel 2: attention per (r,h,half) ----------
// Swapped-operand: S^T = mfma(K, Q) so each lane owns one q-row.
// No LDS, no barriers. P transpose absorbed into V-operand k-slot mapping.
__global__ __launch_bounds__(256) void attn_kernel(
    const unsigned short* __restrict__ Qa, const unsigned short* __restrict__ Ka,
    const unsigned short* __restrict__ Vt, const unsigned short* __restrict__ G,
    const float* __restrict__ bias, unsigned short* __restrict__ og)
{
    int bx = blockIdx.x;
    int r = bx >> 4, h = (bx >> 1) & 7, half = bx & 1;
    int tid = threadIdx.x;
    int w = tid >> 6, lane = tid & 63;
    int c = lane & 15, g = lane >> 4;

    size_t base = ((size_t)(r*8 + h)) * (256*32);
    const unsigned short* Kg = Ka + base;
    const unsigned short* Qg = Qa + base;
    const unsigned short* Vg = Vt + base;           // [d][s] layout
    const float* biash = bias + (size_t)h * 65536;
    const float nrm = 0.17677669529663687f;

    for (int mi = 0; mi < 2; ++mi) {
        int qrow = half*128 + w*32 + mi*16;

        // QK^T (swapped): s[n][i] = S[q=qrow+c][k=16n+4g+i] (pre-scale)
        short8 qf = *(const short8*)(Qg + (size_t)(qrow + c)*32 + g*8);
        f32x4 s[16];
        #pragma unroll
        for (int n = 0; n < 16; ++n) {
            short8 kf = *(const short8*)(Kg + (size_t)(n*16 + c)*32 + g*8);
            f32x4 z = 0.0f;
            s[n] = __builtin_amdgcn_mfma_f32_16x16x32_bf16(kf, qf, z, 0, 0, 0);
        }

        // scale + bias (float4, contiguous per lane) + rowmax
        float mx = -1e30f;
        #pragma unroll
        for (int n = 0; n < 16; ++n) {
            f32x4 bv = *(const f32x4*)(biash + (size_t)(qrow + c)*256 + n*16 + g*4);
            #pragma unroll
            for (int i = 0; i < 4; ++i) {
                float v = s[n][i]*nrm + bv[i];
                s[n][i] = v;
                mx = fmaxf(mx, v);
            }
        }
        mx = fmaxf(mx, __shfl_xor(mx, 16));
        mx = fmaxf(mx, __shfl_xor(mx, 32));

        float sum = 0.f;
        #pragma unroll
        for (int n = 0; n < 16; ++n)
            #pragma unroll
            for (int i = 0; i < 4; ++i) {
                float p = __expf(s[n][i] - mx);
                s[n][i] = p;
                sum += p;
            }
        sum += __shfl_xor(sum, 16);
        sum += __shfl_xor(sum, 32);
        float inv = 1.0f / sum;

        // normalize + pack own row to bf16 pairs
        unsigned int pk[16][2];
        #pragma unroll
        for (int n = 0; n < 16; ++n) {
            pk[n][0] = pack2(s[n][0]*inv, s[n][1]*inv);
            pk[n][1] = pack2(s[n][2]*inv, s[n][3]*inv);
        }

        // PV: k-slot mapping kslot=8g+j -> k = 32t + 16*(j>=4) + 4g + (j&3)
        // => A-frag is the lane's OWN pk values; B reads V^T at permuted k.
        f32x4 o[2];
        o[0] = 0.0f; o[1] = 0.0f;
        #pragma unroll
        for (int t = 0; t < 8; ++t) {
            u32x4 aw; aw[0] = pk[2*t][0]; aw[1] = pk[2*t][1];
            aw[2] = pk[2*t+1][0]; aw[3] = pk[2*t+1][1];
            short8 a = __builtin_bit_cast(short8, aw);
            #pragma unroll
            for (int n2 = 0; n2 < 2; ++n2) {
                const unsigned short* vp = Vg + (size_t)(n2*16 + c)*256 + t*32 + g*4;
                s16x4 lo = *(const s16x4*)vp;
                s16x4 hi = *(const s16x4*)(vp + 16);
                short8 b;
                b[0]=lo[0]; b[1]=lo[1]; b[2]=lo[2]; b[3]=lo[3];
                b[4]=hi[0]; b[5]=hi[1]; b[6]=hi[2]; b[7]=hi[3];
                o[n2] = __builtin_amdgcn_mfma_f32_16x16x32_bf16(a, b, o[n2], 0, 0, 0);
            }
        }

        // epilogue: gate + write og; lane (c,g) holds O[q=qrow+4g+i][d=n2*16+c]
        #pragma unroll
        for (int n2 = 0; n2 < 2; ++n2) {
            #pragma unroll
            for (int i = 0; i < 4; ++i) {
                size_t gidx = ((size_t)(r*256 + qrow + g*4 + i)) * 256 + h*32 + n2*16 + c;
                float gate = bf2f(G[gidx]);
                og[gidx] = (unsigned short)bfbits(o[n2][i] * gate);
            }
        }
    }
}

// ---------- kernel 3: output projection ----------
__global__ __launch_bounds__(256) void oproj_kernel(
    const unsigned short* __restrict__ og, const unsigned short* __restrict__ wt_o,
    const float* __restrict__ bo, float* __restrict__ out)
{
    int rb = blockIdx.x;
    int row0 = rb * 64;
    int tid = threadIdx.x;
    int w = tid >> 6, lane = tid & 63;
    int c = lane & 15, g = lane >> 4;
    int col0 = w * 64;

    f32x4 acc[4][4];
    #pragma unroll
    for (int m = 0; m < 4; m++)
        #pragma unroll
        for (int n = 0; n < 4; n++)
            acc[m][n] = 0.0f;

    for (int step = 0; step < 8; ++step) {
        int koff = step * 32 + g * 8;
        short8 a[4], b[4];
        #pragma unroll
        for (int m = 0; m < 4; m++)
            a[m] = *(const short8*)(og + (size_t)(row0 + m*16 + c) * 256 + koff);
        #pragma unroll
        for (int n = 0; n < 4; n++)
            b[n] = *(const short8*)(wt_o + (size_t)(col0 + n*16 + c) * 256 + koff);
        #pragma unroll
        for (int m = 0; m < 4; m++)
            #pragma unroll
            for (int n = 0; n < 4; n++)
                acc[m][n] = __builtin_amdgcn_mfma_f32_16x16x32_bf16(a[m], b[n], acc[m][n], 0, 0, 0);
    }

    #pragma unroll
    for (int m = 0; m < 4; m++) {
        #pragma unroll
        for (int n = 0; n < 4; n++) {
            int col = col0 + n*16 + c;
            float bv = bo[col];
            #pragma unroll
            for (int i = 0; i < 4; i++) {
                int row = row0 + m*16 + g*4 + i;
                out[(size_t)row * 256 + col] = acc[m][n][i] + bv;
            }
        }
    }
}

extern "C" void kernel_launch(void* const* d_in, const int* in_sizes, int n_in,
                              void* d_out, int out_size, void* d_ws, size_t ws_size,
                              hipStream_t stream) {
    const float* qx   = (const float*)d_in[0];
    const float* kx   = (const float*)d_in[1];
    const float* vx   = (const float*)d_in[2];
    const float* bias = (const float*)d_in[3];
    const float* Wq   = (const float*)d_in[4];
    const float* Wk   = (const float*)d_in[5];
    const float* Wv   = (const float*)d_in[6];
    const float* Wo   = (const float*)d_in[7];
    const float* bo   = (const float*)d_in[8];
    const float* Wg   = (const float*)d_in[9];
    const float* bg   = (const float*)d_in[10];

    uint8_t* ws = (uint8_t*)d_ws;
    unsigned short* wt = (unsigned short*)ws;                         // 5*65536 elems
    unsigned short* Qa = (unsigned short*)(ws + (1u<<20));
    unsigned short* Ka = (unsigned short*)(ws + (1u<<20) + 1u*(1u<<24));
    unsigned short* Va = (unsigned short*)(ws + (1u<<20) + 2u*(1u<<24));
    unsigned short* G  = (unsigned short*)(ws + (1u<<20) + 3u*(1u<<24));
    unsigned short* og = (unsigned short*)(ws + (1u<<20) + 4u*(1u<<24));

    hipLaunchKernelGGL(wt_kernel, dim3(1280), dim3(256), 0, stream, Wq, Wk, Wv, Wg, Wo, wt);
    hipLaunchKernelGGL(proj_kernel, dim3(2048), dim3(256), 0, stream, qx, kx, vx, bg, wt, Qa, Ka, Va, G);
    hipLaunchKernelGGL(attn_kernel, dim3(2048), dim3(256), 0, stream, Qa, Ka, Va, G, bias, og);
    hipLaunchKernelGGL(oproj_kernel, dim3(512), dim3(256), 0, stream, og, wt + 4*65536, bo, (float*)d_out);
}

// Round 4
// 185.767 us; speedup vs baseline: 1.6251x; 1.3821x over previous
//
#include <hip/hip_runtime.h>
#include <hip/hip_bf16.h>
#include <cstdint>
#include <cstddef>

typedef __attribute__((ext_vector_type(8))) short short8;
typedef __attribute__((ext_vector_type(4))) short s16x4;
typedef __attribute__((ext_vector_type(4))) unsigned short u16x4;
typedef __attribute__((ext_vector_type(4))) float f32x4;
typedef __attribute__((ext_vector_type(4))) unsigned int u32x4;

__device__ __forceinline__ short bfbits(float f) {
    __bf16 h = (__bf16)f;
    return __builtin_bit_cast(short, h);
}
__device__ __forceinline__ float bf2f(unsigned short b) {
    union { uint32_t u; float f; } v; v.u = ((uint32_t)b) << 16;
    return v.f;
}
__device__ __forceinline__ unsigned int pack2(float x, float y) {
    return (unsigned int)(unsigned short)bfbits(x) |
           ((unsigned int)(unsigned short)bfbits(y) << 16);
}

// ---------- kernel 0: weight transpose + bf16 convert ----------
// wt[mat][n][k] = bf16(W[mat][k][n]),  mat: 0=Wq 1=Wk 2=Wv 3=Wg 4=Wo
__global__ void wt_kernel(const float* __restrict__ Wq, const float* __restrict__ Wk,
                          const float* __restrict__ Wv, const float* __restrict__ Wg,
                          const float* __restrict__ Wo, unsigned short* __restrict__ wt)
{
    int mat = blockIdx.x >> 8;
    int n   = blockIdx.x & 255;
    const float* W = (mat==0)?Wq:(mat==1)?Wk:(mat==2)?Wv:(mat==3)?Wg:Wo;
    int k = threadIdx.x;
    wt[((size_t)mat*256 + n)*256 + k] = (unsigned short)bfbits(W[(size_t)k*256 + n]);
}

// ---------- proj K-loop (templated on operand order) ----------
// SWAP=0: acc[m][n] = mfma(a[m], b[n], .)  -> D[row=x_s][col=w_d]
// SWAP=1: acc[m][n] = mfma(b[n], a[m], .)  -> D[row=w_d][col=x_s]
template<int SWAP>
__device__ __forceinline__ void proj_mfma_loop(
    const unsigned short* As, const unsigned short* Wt,
    int col0, int c, int g, f32x4 acc[4][4])
{
    short8 pb[4];
    #pragma unroll
    for (int n = 0; n < 4; ++n)
        pb[n] = *(const short8*)(Wt + (size_t)(col0 + n*16 + c) * 256 + g*8);

    #pragma unroll
    for (int step = 0; step < 8; ++step) {
        short8 b[4];
        #pragma unroll
        for (int n = 0; n < 4; ++n) b[n] = pb[n];
        if (step < 7) {
            int koff = (step + 1) * 32 + g * 8;
            #pragma unroll
            for (int n = 0; n < 4; ++n)
                pb[n] = *(const short8*)(Wt + (size_t)(col0 + n*16 + c) * 256 + koff);
        }
        short8 a[4];
        #pragma unroll
        for (int m = 0; m < 4; ++m) {
            int row = m * 16 + c;
            int off = row * 512 + ((step * 64 + g * 16) ^ ((row & 31) << 4));
            a[m] = *(const short8*)((const char*)As + off);
        }
        #pragma unroll
        for (int m = 0; m < 4; ++m)
            #pragma unroll
            for (int n = 0; n < 4; ++n) {
                if (SWAP)
                    acc[m][n] = __builtin_amdgcn_mfma_f32_16x16x32_bf16(b[n], a[m], acc[m][n], 0, 0, 0);
                else
                    acc[m][n] = __builtin_amdgcn_mfma_f32_16x16x32_bf16(a[m], b[n], acc[m][n], 0, 0, 0);
            }
    }
}

// ---------- kernel 1: fused projections ----------
// grid = 512 row-blocks * 4 projections. p: 0=Q 1=K 2=V 3=G(gate)
// Q/K -> [r][h][s][32]; V -> transposed [r][h][d][s]; G = sigmoid -> [rq][256].
__global__ __launch_bounds__(256) void proj_kernel(
    const float* __restrict__ qx, const float* __restrict__ kx, const float* __restrict__ vx,
    const float* __restrict__ bg, const unsigned short* __restrict__ wt,
    unsigned short* __restrict__ Qa, unsigned short* __restrict__ Ka,
    unsigned short* __restrict__ Va, unsigned short* __restrict__ G)
{
    __shared__ __align__(16) unsigned short As[64 * 256]; // bf16 X-tile, XOR-swizzled

    int bx = blockIdx.x;
    int p  = bx & 3;
    int rb = bx >> 2;
    int row0 = rb * 64;
    int tid = threadIdx.x;
    int lane = tid & 63;
    int c = lane & 15, g = lane >> 4;
    int col0 = (tid >> 6) * 64;

    const float* X = (p == 1) ? kx : (p == 2) ? vx : qx;
    const unsigned short* Wt = wt + (size_t)p * 65536;

    // ---- stage X tile (64 rows x 256 k) as bf16, swizzled ----
    {
        int l32 = tid & 31;
        int rg  = tid >> 5;
        #pragma unroll
        for (int j = 0; j < 8; ++j) {
            int row = j * 8 + rg;
            const float* src = X + (size_t)(row0 + row) * 256 + l32 * 8;
            f32x4 lo = *(const f32x4*)src;
            f32x4 hi = *(const f32x4*)(src + 4);
            u32x4 pkv;
            pkv[0] = pack2(lo[0], lo[1]); pkv[1] = pack2(lo[2], lo[3]);
            pkv[2] = pack2(hi[0], hi[1]); pkv[3] = pack2(hi[2], hi[3]);
            int off = row * 512 + ((l32 * 16) ^ ((row & 31) << 4));
            *(u32x4*)((char*)As + off) = pkv;
        }
    }
    __syncthreads();

    f32x4 acc[4][4];
    #pragma unroll
    for (int m = 0; m < 4; ++m)
        #pragma unroll
        for (int n = 0; n < 4; ++n)
            acc[m][n] = 0.0f;

    if (p == 2) proj_mfma_loop<0>(As, Wt, col0, c, g, acc);
    else        proj_mfma_loop<1>(As, Wt, col0, c, g, acc);

    int r_ = row0 >> 8;
    int s0base = row0 & 255;

    if (p == 2) {
        // unswapped: value V[s = row0+m*16+4g+i][d = col0+n*16+c] -> Va[rh][d][s]
        #pragma unroll
        for (int m = 0; m < 4; ++m) {
            int s0 = s0base + m * 16 + 4 * g;
            #pragma unroll
            for (int n = 0; n < 4; ++n) {
                int dcol = col0 + n * 16 + c;
                int h_ = dcol >> 5, d_ = dcol & 31;
                u16x4 st;
                #pragma unroll
                for (int i = 0; i < 4; ++i) st[i] = (unsigned short)bfbits(acc[m][n][i]);
                *(u16x4*)(Va + ((size_t)((r_*8 + h_)*32 + d_)) * 256 + s0) = st;
            }
        }
    } else if (p == 3) {
        // swapped: value X@Wg[row = row0+m*16+c][col = col0+n*16+4g+i]
        #pragma unroll
        for (int n = 0; n < 4; ++n) {
            int colb = col0 + n * 16 + 4 * g;
            f32x4 bgv = *(const f32x4*)(bg + colb);
            #pragma unroll
            for (int m = 0; m < 4; ++m) {
                int rq = row0 + m * 16 + c;
                u16x4 st;
                #pragma unroll
                for (int i = 0; i < 4; ++i) {
                    float s = 1.0f / (1.0f + __expf(-(acc[m][n][i] + bgv[i])));
                    st[i] = (unsigned short)bfbits(s);
                }
                *(u16x4*)(G + (size_t)rq * 256 + colb) = st;
            }
        }
    } else {
        unsigned short* dst = p ? Ka : Qa;
        #pragma unroll
        for (int n = 0; n < 4; ++n) {
            int colb = col0 + n * 16 + 4 * g;
            int h_ = colb >> 5, d0 = colb & 31;
            #pragma unroll
            for (int m = 0; m < 4; ++m) {
                int s_ = s0base + m * 16 + c;
                u16x4 st;
                #pragma unroll
                for (int i = 0; i < 4; ++i) st[i] = (unsigned short)bfbits(acc[m][n][i]);
                *(u16x4*)(dst + ((size_t)((r_*8 + h_)*256 + s_)) * 32 + d0) = st;
            }
        }
    }
}

// ---------- kernel 2: attention per (r,h,half) ----------
// Swapped-operand: S^T = mfma(K, Q) so each lane owns one q-row.
// No LDS, no barriers. P transpose absorbed into V-operand k-slot mapping.
__global__ __launch_bounds__(256) void attn_kernel(
    const unsigned short* __restrict__ Qa, const unsigned short* __restrict__ Ka,
    const unsigned short* __restrict__ Vt, const unsigned short* __restrict__ G,
    const float* __restrict__ bias, unsigned short* __restrict__ og)
{
    int bx = blockIdx.x;
    int r = bx >> 4, h = (bx >> 1) & 7, half = bx & 1;
    int tid = threadIdx.x;
    int w = tid >> 6, lane = tid & 63;
    int c = lane & 15, g = lane >> 4;

    size_t base = ((size_t)(r*8 + h)) * (256*32);
    const unsigned short* Kg = Ka + base;
    const unsigned short* Qg = Qa + base;
    const unsigned short* Vg = Vt + base;           // [d][s] layout
    const float* biash = bias + (size_t)h * 65536;
    const float nrm = 0.17677669529663687f;

    for (int mi = 0; mi < 2; ++mi) {
        int qrow = half*128 + w*32 + mi*16;

        // QK^T (swapped): s[n][i] = S[q=qrow+c][k=16n+4g+i] (pre-scale)
        short8 qf = *(const short8*)(Qg + (size_t)(qrow + c)*32 + g*8);
        f32x4 s[16];
        #pragma unroll
        for (int n = 0; n < 16; ++n) {
            short8 kf = *(const short8*)(Kg + (size_t)(n*16 + c)*32 + g*8);
            f32x4 z = 0.0f;
            s[n] = __builtin_amdgcn_mfma_f32_16x16x32_bf16(kf, qf, z, 0, 0, 0);
        }

        // scale + bias (float4, contiguous per lane) + rowmax
        float mx = -1e30f;
        #pragma unroll
        for (int n = 0; n < 16; ++n) {
            f32x4 bv = *(const f32x4*)(biash + (size_t)(qrow + c)*256 + n*16 + g*4);
            #pragma unroll
            for (int i = 0; i < 4; ++i) {
                float v = s[n][i]*nrm + bv[i];
                s[n][i] = v;
                mx = fmaxf(mx, v);
            }
        }
        mx = fmaxf(mx, __shfl_xor(mx, 16));
        mx = fmaxf(mx, __shfl_xor(mx, 32));

        float sum = 0.f;
        #pragma unroll
        for (int n = 0; n < 16; ++n)
            #pragma unroll
            for (int i = 0; i < 4; ++i) {
                float p = __expf(s[n][i] - mx);
                s[n][i] = p;
                sum += p;
            }
        sum += __shfl_xor(sum, 16);
        sum += __shfl_xor(sum, 32);
        float inv = 1.0f / sum;

        // normalize + pack own row to bf16 pairs
        unsigned int pk[16][2];
        #pragma unroll
        for (int n = 0; n < 16; ++n) {
            pk[n][0] = pack2(s[n][0]*inv, s[n][1]*inv);
            pk[n][1] = pack2(s[n][2]*inv, s[n][3]*inv);
        }

        // PV: k-slot mapping kslot=8g+j -> k = 32t + 16*(j>=4) + 4g + (j&3)
        // => A-frag is the lane's OWN pk values; B reads V^T at permuted k.
        f32x4 o[2];
        o[0] = 0.0f; o[1] = 0.0f;
        #pragma unroll
        for (int t = 0; t < 8; ++t) {
            u32x4 aw; aw[0] = pk[2*t][0]; aw[1] = pk[2*t][1];
            aw[2] = pk[2*t+1][0]; aw[3] = pk[2*t+1][1];
            short8 a = __builtin_bit_cast(short8, aw);
            #pragma unroll
            for (int n2 = 0; n2 < 2; ++n2) {
                const unsigned short* vp = Vg + (size_t)(n2*16 + c)*256 + t*32 + g*4;
                s16x4 lo = *(const s16x4*)vp;
                s16x4 hi = *(const s16x4*)(vp + 16);
                short8 b;
                b[0]=lo[0]; b[1]=lo[1]; b[2]=lo[2]; b[3]=lo[3];
                b[4]=hi[0]; b[5]=hi[1]; b[6]=hi[2]; b[7]=hi[3];
                o[n2] = __builtin_amdgcn_mfma_f32_16x16x32_bf16(a, b, o[n2], 0, 0, 0);
            }
        }

        // epilogue: gate + write og; lane (c,g) holds O[q=qrow+4g+i][d=n2*16+c]
        #pragma unroll
        for (int n2 = 0; n2 < 2; ++n2) {
            #pragma unroll
            for (int i = 0; i < 4; ++i) {
                size_t gidx = ((size_t)(r*256 + qrow + g*4 + i)) * 256 + h*32 + n2*16 + c;
                float gate = bf2f(G[gidx]);
                og[gidx] = (unsigned short)bfbits(o[n2][i] * gate);
            }
        }
    }
}

// ---------- kernel 3: output projection (swapped, coalesced f32x4 stores) ----------
__global__ __launch_bounds__(256) void oproj_kernel(
    const unsigned short* __restrict__ og, const unsigned short* __restrict__ wt_o,
    const float* __restrict__ bo, float* __restrict__ out)
{
    int row0 = blockIdx.x * 64;
    int tid = threadIdx.x;
    int lane = tid & 63;
    int c = lane & 15, g = lane >> 4;
    int col0 = (tid >> 6) * 64;

    f32x4 acc[4][4];
    #pragma unroll
    for (int m = 0; m < 4; ++m)
        #pragma unroll
        for (int n = 0; n < 4; ++n)
            acc[m][n] = 0.0f;

    short8 pa[4], pb[4];
    #pragma unroll
    for (int m = 0; m < 4; ++m)
        pa[m] = *(const short8*)(og + (size_t)(row0 + m*16 + c) * 256 + g*8);
    #pragma unroll
    for (int n = 0; n < 4; ++n)
        pb[n] = *(const short8*)(wt_o + (size_t)(col0 + n*16 + c) * 256 + g*8);

    #pragma unroll
    for (int step = 0; step < 8; ++step) {
        short8 a[4], b[4];
        #pragma unroll
        for (int m = 0; m < 4; ++m) a[m] = pa[m];
        #pragma unroll
        for (int n = 0; n < 4; ++n) b[n] = pb[n];
        if (step < 7) {
            int koff = (step + 1) * 32 + g * 8;
            #pragma unroll
            for (int m = 0; m < 4; ++m)
                pa[m] = *(const short8*)(og + (size_t)(row0 + m*16 + c) * 256 + koff);
            #pragma unroll
            for (int n = 0; n < 4; ++n)
                pb[n] = *(const short8*)(wt_o + (size_t)(col0 + n*16 + c) * 256 + koff);
        }
        // swapped: acc[m][n] row-index = W col (4g+i), col-index = og row (c)
        #pragma unroll
        for (int m = 0; m < 4; ++m)
            #pragma unroll
            for (int n = 0; n < 4; ++n)
                acc[m][n] = __builtin_amdgcn_mfma_f32_16x16x32_bf16(b[n], a[m], acc[m][n], 0, 0, 0);
    }

    #pragma unroll
    for (int n = 0; n < 4; ++n) {
        int colb = col0 + n * 16 + 4 * g;
        f32x4 bov = *(const f32x4*)(bo + colb);
        #pragma unroll
        for (int m = 0; m < 4; ++m) {
            int row = row0 + m * 16 + c;
            f32x4 st = acc[m][n] + bov;
            *(f32x4*)(out + (size_t)row * 256 + colb) = st;
        }
    }
}

extern "C" void kernel_launch(void* const* d_in, const int* in_sizes, int n_in,
                              void* d_out, int out_size, void* d_ws, size_t ws_size,
                              hipStream_t stream) {
    const float* qx   = (const float*)d_in[0];
    const float* kx   = (const float*)d_in[1];
    const float* vx   = (const float*)d_in[2];
    const float* bias = (const float*)d_in[3];
    const float* Wq   = (const float*)d_in[4];
    const float* Wk   = (const float*)d_in[5];
    const float* Wv   = (const float*)d_in[6];
    const float* Wo   = (const float*)d_in[7];
    const float* bo   = (const float*)d_in[8];
    const float* Wg   = (const float*)d_in[9];
    const float* bg   = (const float*)d_in[10];

    uint8_t* ws = (uint8_t*)d_ws;
    unsigned short* wt = (unsigned short*)ws;                         // 5*65536 elems
    unsigned short* Qa = (unsigned short*)(ws + (1u<<20));
    unsigned short* Ka = (unsigned short*)(ws + (1u<<20) + 1u*(1u<<24));
    unsigned short* Va = (unsigned short*)(ws + (1u<<20) + 2u*(1u<<24));
    unsigned short* G  = (unsigned short*)(ws + (1u<<20) + 3u*(1u<<24));
    unsigned short* og = (unsigned short*)(ws + (1u<<20) + 4u*(1u<<24));

    hipLaunchKernelGGL(wt_kernel, dim3(1280), dim3(256), 0, stream, Wq, Wk, Wv, Wg, Wo, wt);
    hipLaunchKernelGGL(proj_kernel, dim3(2048), dim3(256), 0, stream, qx, kx, vx, bg, wt, Qa, Ka, Va, G);
    hipLaunchKernelGGL(attn_kernel, dim3(2048), dim3(256), 0, stream, Qa, Ka, Va, G, bias, og);
    hipLaunchKernelGGL(oproj_kernel, dim3(512), dim3(256), 0, stream, og, wt + 4*65536, bo, (float*)d_out);
}